// Round 5
// baseline (147.538 us; speedup 1.0000x reference)
//
#include <hip/hip_runtime.h>
#include <hip/hip_bf16.h>

// GCNConv: out = A @ (X @ W)
// Stage 0: W_T[n][k] = bf16(W[k][n])                       (prep kernel, d_ws)
// Stage 1: Xp_bf16 = bf16(X @ W)   bf16 MFMA 16x16x32
//          Full B (64KB bf16) resident in LDS -> single barrier, pipelined k-loop
//          A fragments direct global->reg (no cross-wave A reuse)
// Stage 2: out[i,:] = sum_{e} Xp[colx[e],:]   4 nodes/wave, 16B gathers, fp32 acc

constexpr int D_IN  = 256;
constexpr int D_OUT = 128;
constexpr int BM = 128;
constexpr int BK = 32;
constexpr int LDB = D_IN + 8;   // padded LDS stride in shorts (264, 16B-aligned)

using short8  = __attribute__((ext_vector_type(8))) short;
using float4v = __attribute__((ext_vector_type(4))) float;

__device__ inline ushort f2bf(float f) {
    unsigned u = __float_as_uint(f);
    u = (u + 0x7FFFu + ((u >> 16) & 1u)) >> 16;   // RNE
    return (ushort)u;
}

__device__ inline uint pk2bf(float lo, float hi) {
    float2 t; t.x = lo; t.y = hi;
    __hip_bfloat162 b = __float22bfloat162_rn(t);   // v_cvt_pk_bf16_f32
    return *(uint*)&b;
}

// W[k][n] fp32 -> W_T[n][k] bf16  (128 rows x 256 cols)
__global__ __launch_bounds__(256) void prep_wt(const float* __restrict__ W,
                                               ushort* __restrict__ WT) {
    int id = blockIdx.x * 256 + threadIdx.x;   // 32768 total
    int nn = id >> 8;        // 0..127
    int k  = id & 255;       // 0..255
    WT[nn * 256 + k] = f2bf(W[k * D_OUT + nn]);
}

__global__ __launch_bounds__(256) void gemm_xw(const float* __restrict__ X,
                                               const ushort* __restrict__ WT,
                                               ushort* __restrict__ Xp, int n) {
    __shared__ ushort Bsl[D_OUT * LDB];  // 128 x 264 shorts = 67.6 KB (all of B)
    const int tid  = threadIdx.x;
    const int wave = tid >> 6;
    const int lane = tid & 63;
    const int quad = lane >> 4;
    const int l16  = lane & 15;
    const int row0 = blockIdx.x * BM;

    // Stage ALL of B once: 4096 short8 chunks, 16 per thread, coalesced.
#pragma unroll
    for (int i = 0; i < 16; ++i) {
        int idx = i * 256 + tid;
        int r  = idx >> 5;        // 32 chunks of 8 shorts per 256-short row
        int ch = idx & 31;
        short8 v = *(const short8*)(WT + r * 256 + ch * 8);
        *(short8*)(&Bsl[r * LDB + ch * 8]) = v;
    }

    // A fragment source rows for this lane (clamped; stores are guarded)
    int rA = row0 + wave * 32 + l16;      if (rA > n - 1) rA = n - 1;
    int rB = row0 + wave * 32 + 16 + l16; if (rB > n - 1) rB = n - 1;
    const float* pA = X + (size_t)rA * D_IN + quad * 8;
    const float* pB = X + (size_t)rB * D_IN + quad * 8;

    float4v acc[2][8];
#pragma unroll
    for (int i = 0; i < 2; ++i)
#pragma unroll
        for (int t = 0; t < 8; ++t) acc[i][t] = (float4v){0.f, 0.f, 0.f, 0.f};

    __syncthreads();   // the only barrier

#pragma unroll
    for (int k0 = 0; k0 < D_IN; k0 += BK) {
        // A fragments: direct global -> reg, convert in-reg.
        // lane (quad,l16): A[m=l16][k=quad*8+j], 8 fp32 = 2 dwordx4 per row-tile.
        float4 x0 = *(const float4*)(pA + k0);
        float4 x1 = *(const float4*)(pA + k0 + 4);
        float4 y0 = *(const float4*)(pB + k0);
        float4 y1 = *(const float4*)(pB + k0 + 4);
        uint a0p[4] = { pk2bf(x0.x, x0.y), pk2bf(x0.z, x0.w),
                        pk2bf(x1.x, x1.y), pk2bf(x1.z, x1.w) };
        uint a1p[4] = { pk2bf(y0.x, y0.y), pk2bf(y0.z, y0.w),
                        pk2bf(y1.x, y1.y), pk2bf(y1.z, y1.w) };
        short8 a0 = *(short8*)a0p;
        short8 a1 = *(short8*)a1p;

#pragma unroll
        for (int t = 0; t < 8; ++t) {
            // B fragment: lane holds B[k=quad*8+j][nn = t*16 + l16]
            short8 b = *(const short8*)(&Bsl[(t * 16 + l16) * LDB + k0 + quad * 8]);
            acc[0][t] = __builtin_amdgcn_mfma_f32_16x16x32_bf16(a0, b, acc[0][t], 0, 0, 0);
            acc[1][t] = __builtin_amdgcn_mfma_f32_16x16x32_bf16(a1, b, acc[1][t], 0, 0, 0);
        }
    }

    // Epilogue: C/D layout col = l16, row = quad*4 + reg
#pragma unroll
    for (int rt = 0; rt < 2; ++rt) {
#pragma unroll
        for (int t = 0; t < 8; ++t) {
#pragma unroll
            for (int r = 0; r < 4; ++r) {
                int row = row0 + wave * 32 + rt * 16 + quad * 4 + r;
                if (row < n)
                    Xp[(size_t)row * D_OUT + t * 16 + l16] = f2bf(acc[rt][t][r]);
            }
        }
    }
}

// 4 nodes per wave: 16 lanes per node, lane covers 8 of 128 cols (16B per edge).
// Degree-16 fast path: 16 uint4 gathers per node all in flight.
__global__ __launch_bounds__(256) void spmm_agg(const ushort* __restrict__ Xp,
                                                const int* __restrict__ rowp,
                                                const int* __restrict__ colx,
                                                float* __restrict__ out, int n) {
    const int lane   = threadIdx.x & 63;
    const int sub    = lane >> 4;          // 0..3 : node within wave
    const int l16    = lane & 15;
    const int node   = blockIdx.x * 16 + (threadIdx.x >> 6) * 4 + sub;
    if (node >= n) return;
    const int e0 = rowp[node];
    const int e1 = rowp[node + 1];
    const ushort* src = Xp + l16 * 8;      // 16B slice of the 256B row
    float a[8];
#pragma unroll
    for (int i = 0; i < 8; ++i) a[i] = 0.f;
    if (e1 - e0 == 16) {
        int c[16];
#pragma unroll
        for (int i = 0; i < 16; ++i) c[i] = colx[e0 + i];
        uint4 v[16];
#pragma unroll
        for (int i = 0; i < 16; ++i)
            v[i] = *(const uint4*)(src + (size_t)c[i] * D_OUT);  // 16 in flight
#pragma unroll
        for (int i = 0; i < 16; ++i) {
            a[0] += __uint_as_float(v[i].x << 16);
            a[1] += __uint_as_float(v[i].x & 0xFFFF0000u);
            a[2] += __uint_as_float(v[i].y << 16);
            a[3] += __uint_as_float(v[i].y & 0xFFFF0000u);
            a[4] += __uint_as_float(v[i].z << 16);
            a[5] += __uint_as_float(v[i].z & 0xFFFF0000u);
            a[6] += __uint_as_float(v[i].w << 16);
            a[7] += __uint_as_float(v[i].w & 0xFFFF0000u);
        }
    } else {
        for (int e = e0; e < e1; ++e) {
            uint4 v = *(const uint4*)(src + (size_t)colx[e] * D_OUT);
            a[0] += __uint_as_float(v.x << 16);
            a[1] += __uint_as_float(v.x & 0xFFFF0000u);
            a[2] += __uint_as_float(v.y << 16);
            a[3] += __uint_as_float(v.y & 0xFFFF0000u);
            a[4] += __uint_as_float(v.z << 16);
            a[5] += __uint_as_float(v.z & 0xFFFF0000u);
            a[6] += __uint_as_float(v.w << 16);
            a[7] += __uint_as_float(v.w & 0xFFFF0000u);
        }
    }
    float* dst = out + (size_t)node * D_OUT + l16 * 8;
    *(float4*)(dst)     = make_float4(a[0], a[1], a[2], a[3]);
    *(float4*)(dst + 4) = make_float4(a[4], a[5], a[6], a[7]);
}

extern "C" void kernel_launch(void* const* d_in, const int* in_sizes, int n_in,
                              void* d_out, int out_size, void* d_ws, size_t ws_size,
                              hipStream_t stream) {
    const float* X    = (const float*)d_in[0];
    const float* W    = (const float*)d_in[1];
    const int*   rowp = (const int*)d_in[2];
    const int*   colx = (const int*)d_in[3];
    float*       out  = (float*)d_out;

    ushort* WT = (ushort*)d_ws;                       // 128*256*2 = 64 KB
    ushort* Xp = (ushort*)((char*)d_ws + 65536);      // n*128*2 = 12.8 MB

    const int n = in_sizes[0] / D_IN;                 // 50000

    prep_wt<<<dim3(128), dim3(256), 0, stream>>>(W, WT);
    gemm_xw<<<dim3((n + BM - 1) / BM), dim3(256), 0, stream>>>(X, WT, Xp, n);
    spmm_agg<<<dim3((n + 15) / 16), dim3(256), 0, stream>>>(Xp, rowp, colx, out, n);
}